// Round 2
// baseline (585.742 us; speedup 1.0000x reference)
//
#include <hip/hip_runtime.h>
#include <hip/hip_bf16.h>

#define N_PTS 100000
#define KNN   16
#define NK    (N_PTS * KNN)
#define CIN   64
#define CMID  64
#define COUT  128

// ---------------- ws layout (bytes) ----------------
// [0, 200000)          p0: partial counts slice 0 (ushort[100000])
// [200000, 400000)     p1: partial counts slice 1 (ushort[100000])
// [401408, 402944)     stats: S1[64] Q1[64] S2[128] Q2[128]  (f32, memset 0)
// [405504, +25.6MB)    z1 (N*64 f32)  -- later aliased as h2 (N*128 bf16)
// [26005504, +51.2MB)  z2 (N*128 f32)
#define OFF_STATS 401408
#define OFF_Z1    405504
#define OFF_Z2    26005504

#define SEG_CNT   25000      // counters per segment (4 segments)
#define SEG_U32   12500      // packed uints per segment
#define GEMM1_BLKS 391       // ceil(100000/256)

__device__ __forceinline__ unsigned short f2bf(float f) {
    unsigned u = __float_as_uint(f);
    unsigned r = (u + 0x7fffu + ((u >> 16) & 1u)) >> 16;   // RNE
    return (unsigned short)r;
}

// ---- K1: blocks [0,391) do z1 = feat@W1+b1 ; blocks [391,399) do segmented hist ----
__global__ __launch_bounds__(256) void k1_gemm1_hist(const float* __restrict__ feat,
                                                     const float* __restrict__ W1,
                                                     const float* __restrict__ b1,
                                                     const int* __restrict__ idx,
                                                     float* __restrict__ z1,
                                                     unsigned short* __restrict__ pc) {
    __shared__ unsigned int smem[SEG_U32];     // 50 KB; gemm path uses first 16 KB as Wl

    if (blockIdx.x >= GEMM1_BLKS) {
        // ---------- histogram path ----------
        int hb   = blockIdx.x - GEMM1_BLKS;    // 0..7
        int seg  = hb >> 1;                    // 0..3
        int slc  = hb & 1;                     // 0..1
        int base = seg * SEG_CNT;

        for (int i = threadIdx.x; i < SEG_U32; i += 256) smem[i] = 0;
        __syncthreads();

        const int4* ip = (const int4*)idx;     // 400000 int4 total
        int s = slc * 200000, e = s + 200000;
        for (int i = s + threadIdx.x; i < e; i += 256) {
            int4 v = ip[i];
            int a;
            a = v.x - base; if ((unsigned)a < (unsigned)SEG_CNT)
                atomicAdd(&smem[a >> 1], 1u << ((a & 1) * 16));
            a = v.y - base; if ((unsigned)a < (unsigned)SEG_CNT)
                atomicAdd(&smem[a >> 1], 1u << ((a & 1) * 16));
            a = v.z - base; if ((unsigned)a < (unsigned)SEG_CNT)
                atomicAdd(&smem[a >> 1], 1u << ((a & 1) * 16));
            a = v.w - base; if ((unsigned)a < (unsigned)SEG_CNT)
                atomicAdd(&smem[a >> 1], 1u << ((a & 1) * 16));
        }
        __syncthreads();

        // plain coalesced flush: two 16-bit counters per uint, adjacent in memory
        unsigned int* outp = (unsigned int*)(pc + (size_t)slc * N_PTS) + seg * SEG_U32;
        for (int i = threadIdx.x; i < SEG_U32; i += 256) outp[i] = smem[i];
        return;
    }

    // ---------- gemm1 path ----------
    float* Wl = (float*)smem;                  // 64*64 f32 = 16 KB
    for (int i = threadIdx.x; i < CIN * CMID / 4; i += 256)
        ((float4*)Wl)[i] = ((const float4*)W1)[i];
    __syncthreads();

    int row = blockIdx.x * 256 + threadIdx.x;
    if (row >= N_PTS) return;

    float acc[CMID];
    #pragma unroll
    for (int j = 0; j < CMID; j++) acc[j] = b1[j];

    const float4* fr = (const float4*)(feat + (size_t)row * CIN);
    #pragma unroll 4
    for (int c4 = 0; c4 < CIN / 4; c4++) {
        float4 f = fr[c4];
        const float* wr = Wl + c4 * 4 * CMID;
        #pragma unroll
        for (int j = 0; j < CMID; j++) acc[j] = fmaf(f.x, wr[j], acc[j]);
        #pragma unroll
        for (int j = 0; j < CMID; j++) acc[j] = fmaf(f.y, wr[CMID + j], acc[j]);
        #pragma unroll
        for (int j = 0; j < CMID; j++) acc[j] = fmaf(f.z, wr[2 * CMID + j], acc[j]);
        #pragma unroll
        for (int j = 0; j < CMID; j++) acc[j] = fmaf(f.w, wr[3 * CMID + j], acc[j]);
    }
    float4* zr = (float4*)(z1 + (size_t)row * CMID);
    #pragma unroll
    for (int j = 0; j < CMID / 4; j++)
        zr[j] = make_float4(acc[4 * j], acc[4 * j + 1], acc[4 * j + 2], acc[4 * j + 3]);
}

// ---- weighted channel stats: S += cnt*z, Q += cnt*z^2  (cnt = p0[row]+p1[row]) ----
template <int C>
__global__ __launch_bounds__(256) void stats_k(const float* __restrict__ z,
                                               const unsigned short* __restrict__ pc,
                                               float* __restrict__ S,
                                               float* __restrict__ Q) {
    const int GP = 256 / C;
    int c = threadIdx.x % C;
    int g = threadIdx.x / C;
    float s = 0.f, q = 0.f;
    for (int row = blockIdx.x * GP + g; row < N_PTS; row += gridDim.x * GP) {
        float cnt = (float)((int)pc[row] + (int)pc[N_PTS + row]);
        float zv  = z[(size_t)row * C + c];
        float cz  = cnt * zv;
        s += cz;
        q = fmaf(cz, zv, q);
    }
    __shared__ float sm[256], qm[256];
    sm[threadIdx.x] = s;
    qm[threadIdx.x] = q;
    __syncthreads();
    if (threadIdx.x < C) {
        float ts = 0.f, tq = 0.f;
        #pragma unroll
        for (int i = 0; i < GP; i++) { ts += sm[threadIdx.x + i * C]; tq += qm[threadIdx.x + i * C]; }
        atomicAdd(&S[threadIdx.x], ts);
        atomicAdd(&Q[threadIdx.x], tq);
    }
}

// ---- gemm2: z2 = relu(z1*A1+B1) @ W2 + b2 ; fin1 fused into prologue ----
__global__ __launch_bounds__(256) void gemm2_k(const float* __restrict__ z1,
                                               const float* __restrict__ S1,
                                               const float* __restrict__ Q1,
                                               const float* __restrict__ g1,
                                               const float* __restrict__ be1,
                                               const float* __restrict__ W2,
                                               const float* __restrict__ b2,
                                               float* __restrict__ z2) {
    __shared__ float Wl[CMID * 64];
    __shared__ float Al[CMID], Bl[CMID];
    int half = blockIdx.y;
    for (int i = threadIdx.x; i < CMID * 64 / 4; i += 256) {
        int c = i >> 4, jj = i & 15;
        ((float4*)Wl)[i] = ((const float4*)W2)[c * (COUT / 4) + half * 16 + jj];
    }
    if (threadIdx.x < CMID) {
        const float inv = 1.0f / (float)NK;
        float m = S1[threadIdx.x] * inv;
        float v = Q1[threadIdx.x] * inv - m * m;
        float a = g1[threadIdx.x] * rsqrtf(v + 1e-5f);
        Al[threadIdx.x] = a;
        Bl[threadIdx.x] = be1[threadIdx.x] - m * a;
    }
    __syncthreads();

    int row = blockIdx.x * 256 + threadIdx.x;
    if (row >= N_PTS) return;

    float acc[64];
    #pragma unroll
    for (int j = 0; j < 64; j++) acc[j] = b2[half * 64 + j];

    const float4* zr = (const float4*)(z1 + (size_t)row * CMID);
    #pragma unroll 2
    for (int c4 = 0; c4 < CMID / 4; c4++) {
        float4 zf = zr[c4];
        int c = c4 * 4;
        float h0 = fmaxf(fmaf(zf.x, Al[c + 0], Bl[c + 0]), 0.f);
        float h1 = fmaxf(fmaf(zf.y, Al[c + 1], Bl[c + 1]), 0.f);
        float h2 = fmaxf(fmaf(zf.z, Al[c + 2], Bl[c + 2]), 0.f);
        float h3 = fmaxf(fmaf(zf.w, Al[c + 3], Bl[c + 3]), 0.f);
        const float* wr = Wl + c * 64;
        #pragma unroll
        for (int j = 0; j < 64; j++) acc[j] = fmaf(h0, wr[j], acc[j]);
        #pragma unroll
        for (int j = 0; j < 64; j++) acc[j] = fmaf(h1, wr[64 + j], acc[j]);
        #pragma unroll
        for (int j = 0; j < 64; j++) acc[j] = fmaf(h2, wr[128 + j], acc[j]);
        #pragma unroll
        for (int j = 0; j < 64; j++) acc[j] = fmaf(h3, wr[192 + j], acc[j]);
    }
    float4* zo = (float4*)(z2 + (size_t)row * COUT + half * 64);
    #pragma unroll
    for (int j = 0; j < 16; j++)
        zo[j] = make_float4(acc[4 * j], acc[4 * j + 1], acc[4 * j + 2], acc[4 * j + 3]);
}

// ---- h2 = bf16(relu(z2*A2+B2)) ; fin2 fused into prologue ----
__global__ __launch_bounds__(256) void h2_k(const float* __restrict__ z2,
                                            const float* __restrict__ S2,
                                            const float* __restrict__ Q2,
                                            const float* __restrict__ g2,
                                            const float* __restrict__ be2,
                                            unsigned short* __restrict__ h2) {
    __shared__ float Al[COUT], Bl[COUT];
    if (threadIdx.x < COUT) {
        const float inv = 1.0f / (float)NK;
        float m = S2[threadIdx.x] * inv;
        float v = Q2[threadIdx.x] * inv - m * m;
        float a = g2[threadIdx.x] * rsqrtf(v + 1e-5f);
        Al[threadIdx.x] = a;
        Bl[threadIdx.x] = be2[threadIdx.x] - m * a;
    }
    __syncthreads();
    int i = blockIdx.x * 256 + threadIdx.x;       // float4-group index over N*128
    if (i >= N_PTS * COUT / 4) return;
    float4 z = ((const float4*)z2)[i];
    int c = (i * 4) & (COUT - 1);
    float h0 = fmaxf(fmaf(z.x, Al[c + 0], Bl[c + 0]), 0.f);
    float h1 = fmaxf(fmaf(z.y, Al[c + 1], Bl[c + 1]), 0.f);
    float h2v = fmaxf(fmaf(z.z, Al[c + 2], Bl[c + 2]), 0.f);
    float h3 = fmaxf(fmaf(z.w, Al[c + 3], Bl[c + 3]), 0.f);
    unsigned lo = (unsigned)f2bf(h0) | ((unsigned)f2bf(h1) << 16);
    unsigned hi = (unsigned)f2bf(h2v) | ((unsigned)f2bf(h3) << 16);
    ((uint2*)h2)[i] = make_uint2(lo, hi);
}

// ---- out[n,c] = max_k h2[idx[n,k],c]   (one wave per point; h2 >= 0 so init 0) ----
__global__ __launch_bounds__(256) void gather_k(const unsigned short* __restrict__ h2,
                                                const int* __restrict__ idx,
                                                float* __restrict__ out) {
    int w = threadIdx.x >> 6;
    int lane = threadIdx.x & 63;
    int n = blockIdx.x * 4 + w;
    if (n >= N_PTS) return;
    const int* ip = idx + n * KNN;
    float m0 = 0.f, m1 = 0.f;
    #pragma unroll
    for (int k = 0; k < KNN; k++) {
        int j = ip[k];
        unsigned v = ((const unsigned*)(h2 + (size_t)j * COUT))[lane];  // 2 packed bf16
        float f0 = __uint_as_float(v << 16);
        float f1 = __uint_as_float(v & 0xffff0000u);
        m0 = fmaxf(m0, f0);
        m1 = fmaxf(m1, f1);
    }
    float2 r; r.x = m0; r.y = m1;
    ((float2*)(out + (size_t)n * COUT))[lane] = r;
}

extern "C" void kernel_launch(void* const* d_in, const int* in_sizes, int n_in,
                              void* d_out, int out_size, void* d_ws, size_t ws_size,
                              hipStream_t stream) {
    const float* feat = (const float*)d_in[0];
    const int*   idx  = (const int*)d_in[1];
    const float* W1   = (const float*)d_in[2];
    const float* b1   = (const float*)d_in[3];
    const float* g1   = (const float*)d_in[4];
    const float* be1  = (const float*)d_in[5];
    const float* W2   = (const float*)d_in[6];
    const float* b2   = (const float*)d_in[7];
    const float* g2   = (const float*)d_in[8];
    const float* be2  = (const float*)d_in[9];
    float* out = (float*)d_out;

    char* ws = (char*)d_ws;
    unsigned short* pc = (unsigned short*)ws;          // p0 then p1, each N_PTS ushort
    float* S1 = (float*)(ws + OFF_STATS);
    float* Q1 = S1 + 64;
    float* S2 = S1 + 128;
    float* Q2 = S1 + 256;
    float* z1 = (float*)(ws + OFF_Z1);
    unsigned short* h2 = (unsigned short*)(ws + OFF_Z1);   // alias: z1 dead before h2 written
    float* z2 = (float*)(ws + OFF_Z2);

    // zero only the stats accumulators (S1,Q1,S2,Q2 = 384 floats)
    hipMemsetAsync(ws + OFF_STATS, 0, 1536, stream);

    k1_gemm1_hist<<<GEMM1_BLKS + 8, 256, 0, stream>>>(feat, W1, b1, idx, z1, pc);
    stats_k<64><<<512, 256, 0, stream>>>(z1, pc, S1, Q1);
    gemm2_k<<<dim3(GEMM1_BLKS, 2), 256, 0, stream>>>(z1, S1, Q1, g1, be1, W2, b2, z2);
    stats_k<128><<<512, 256, 0, stream>>>(z2, pc, S2, Q2);
    h2_k<<<N_PTS * COUT / 4 / 256, 256, 0, stream>>>(z2, S2, Q2, g2, be2, h2);
    gather_k<<<N_PTS / 4, 256, 0, stream>>>(h2, idx, out);
}

// Round 3
// 337.066 us; speedup vs baseline: 1.7378x; 1.7378x over previous
//
#include <hip/hip_runtime.h>
#include <hip/hip_bf16.h>

#define N_PTS 100000
#define KNN   16
#define NK    (N_PTS * KNN)
#define CIN   64
#define CMID  64
#define COUT  128

#define HSLC    32           // histogram slices of the index array
#define SEG_CNT 25000        // counters per segment (4 segments cover 100k)
#define SEG_U32 12500        // packed uints per segment (2 x u16)

// ---------------- ws layout (bytes) ----------------
// [0, 51,200,000)        z2 (N*128 f32); [0, 6.4M) of it first holds pc
//                        (32 partial ushort count arrays) - pc dead before
//                        gemm2 writes z2.
// [51,200,000, +400,000) counts (float, N_PTS)
// [51,600,000, +1,536)   stats: S1[64] Q1[64] S2[128] Q2[128]  (memset 0)
// [51,601,536, +25.6MB)  z1 (N*64 f32) -- later aliased as h2 (N*128 bf16)
// total 77,201,536
#define OFF_Z2    0
#define OFF_CNT   51200000
#define OFF_STATS 51600000
#define OFF_Z1    51601536

__device__ __forceinline__ unsigned short f2bf(float f) {
    unsigned u = __float_as_uint(f);
    unsigned r = (u + 0x7fffu + ((u >> 16) & 1u)) >> 16;   // RNE
    return (unsigned short)r;
}

// ---- 1. segmented LDS histogram: 4 segments x 32 slices = 128 blocks ----
__global__ __launch_bounds__(256) void hist_k(const int* __restrict__ idx,
                                              unsigned short* __restrict__ pc) {
    __shared__ unsigned int smem[SEG_U32];     // 50 KB
    int seg  = blockIdx.x & 3;
    int slc  = blockIdx.x >> 2;                // 0..31
    int base = seg * SEG_CNT;

    for (int i = threadIdx.x; i < SEG_U32; i += 256) smem[i] = 0;
    __syncthreads();

    const int4* ip = (const int4*)idx;         // 400000 int4 total
    const int per = NK / 4 / HSLC;             // 12500 int4 per slice
    int s = slc * per, e = s + per;
    for (int i = s + threadIdx.x; i < e; i += 256) {
        int4 v = ip[i];
        int a;
        a = v.x - base; if ((unsigned)a < (unsigned)SEG_CNT)
            atomicAdd(&smem[a >> 1], 1u << ((a & 1) * 16));
        a = v.y - base; if ((unsigned)a < (unsigned)SEG_CNT)
            atomicAdd(&smem[a >> 1], 1u << ((a & 1) * 16));
        a = v.z - base; if ((unsigned)a < (unsigned)SEG_CNT)
            atomicAdd(&smem[a >> 1], 1u << ((a & 1) * 16));
        a = v.w - base; if ((unsigned)a < (unsigned)SEG_CNT)
            atomicAdd(&smem[a >> 1], 1u << ((a & 1) * 16));
    }
    __syncthreads();

    // coalesced flush of this block's segment into partial array `slc`
    unsigned int* outp = (unsigned int*)(pc + (size_t)slc * N_PTS) + seg * SEG_U32;
    for (int i = threadIdx.x; i < SEG_U32; i += 256) outp[i] = smem[i];
}

// ---- 2. counts[row] = sum over 32 partials (packed u16 pairs, no carry risk) ----
__global__ __launch_bounds__(256) void sum_counts_k(const unsigned short* __restrict__ pc,
                                                    float* __restrict__ counts) {
    int i = blockIdx.x * 256 + threadIdx.x;    // uint-pair index over N_PTS/2
    if (i >= N_PTS / 2) return;
    const unsigned int* p = (const unsigned int*)pc;
    unsigned int u = 0;
    #pragma unroll
    for (int s = 0; s < HSLC; s++) u += p[s * (N_PTS / 2) + i];
    float2 r;
    r.x = (float)(u & 0xffffu);
    r.y = (float)(u >> 16);
    ((float2*)counts)[i] = r;
}

// ---- 3. z1 = feat @ W1 + b1  (one row per thread, 64 fp32 accumulators) ----
__global__ __launch_bounds__(256) void gemm1_k(const float* __restrict__ feat,
                                               const float* __restrict__ W1,
                                               const float* __restrict__ b1,
                                               float* __restrict__ z1) {
    __shared__ float Wl[CIN * CMID];
    for (int i = threadIdx.x; i < CIN * CMID / 4; i += 256)
        ((float4*)Wl)[i] = ((const float4*)W1)[i];
    __syncthreads();

    int row = blockIdx.x * 256 + threadIdx.x;
    if (row >= N_PTS) return;

    float acc[CMID];
    #pragma unroll
    for (int j = 0; j < CMID; j++) acc[j] = b1[j];

    const float4* fr = (const float4*)(feat + (size_t)row * CIN);
    #pragma unroll 4
    for (int c4 = 0; c4 < CIN / 4; c4++) {
        float4 f = fr[c4];
        const float* wr = Wl + c4 * 4 * CMID;
        #pragma unroll
        for (int j = 0; j < CMID; j++) acc[j] = fmaf(f.x, wr[j], acc[j]);
        #pragma unroll
        for (int j = 0; j < CMID; j++) acc[j] = fmaf(f.y, wr[CMID + j], acc[j]);
        #pragma unroll
        for (int j = 0; j < CMID; j++) acc[j] = fmaf(f.z, wr[2 * CMID + j], acc[j]);
        #pragma unroll
        for (int j = 0; j < CMID; j++) acc[j] = fmaf(f.w, wr[3 * CMID + j], acc[j]);
    }
    float4* zr = (float4*)(z1 + (size_t)row * CMID);
    #pragma unroll
    for (int j = 0; j < CMID / 4; j++)
        zr[j] = make_float4(acc[4 * j], acc[4 * j + 1], acc[4 * j + 2], acc[4 * j + 3]);
}

// ---- 4/6. weighted channel stats: S += cnt*z, Q += cnt*z^2 ----
template <int C>
__global__ __launch_bounds__(256) void stats_k(const float* __restrict__ z,
                                               const float* __restrict__ counts,
                                               float* __restrict__ S,
                                               float* __restrict__ Q) {
    const int GP = 256 / C;
    int c = threadIdx.x % C;
    int g = threadIdx.x / C;
    float s = 0.f, q = 0.f;
    for (int row = blockIdx.x * GP + g; row < N_PTS; row += gridDim.x * GP) {
        float cnt = counts[row];
        float zv  = z[(size_t)row * C + c];
        float cz  = cnt * zv;
        s += cz;
        q = fmaf(cz, zv, q);
    }
    __shared__ float sm[256], qm[256];
    sm[threadIdx.x] = s;
    qm[threadIdx.x] = q;
    __syncthreads();
    if (threadIdx.x < C) {
        float ts = 0.f, tq = 0.f;
        #pragma unroll
        for (int i = 0; i < GP; i++) { ts += sm[threadIdx.x + i * C]; tq += qm[threadIdx.x + i * C]; }
        atomicAdd(&S[threadIdx.x], ts);
        atomicAdd(&Q[threadIdx.x], tq);
    }
}

// ---- 5. gemm2: z2 = relu(z1*A1+B1) @ W2 + b2 ; fin1 fused into prologue ----
__global__ __launch_bounds__(256) void gemm2_k(const float* __restrict__ z1,
                                               const float* __restrict__ S1,
                                               const float* __restrict__ Q1,
                                               const float* __restrict__ g1,
                                               const float* __restrict__ be1,
                                               const float* __restrict__ W2,
                                               const float* __restrict__ b2,
                                               float* __restrict__ z2) {
    __shared__ float Wl[CMID * 64];
    __shared__ float Al[CMID], Bl[CMID];
    int half = blockIdx.y;
    for (int i = threadIdx.x; i < CMID * 64 / 4; i += 256) {
        int c = i >> 4, jj = i & 15;
        ((float4*)Wl)[i] = ((const float4*)W2)[c * (COUT / 4) + half * 16 + jj];
    }
    if (threadIdx.x < CMID) {
        const float inv = 1.0f / (float)NK;
        float m = S1[threadIdx.x] * inv;
        float v = Q1[threadIdx.x] * inv - m * m;
        float a = g1[threadIdx.x] * rsqrtf(v + 1e-5f);
        Al[threadIdx.x] = a;
        Bl[threadIdx.x] = be1[threadIdx.x] - m * a;
    }
    __syncthreads();

    int row = blockIdx.x * 256 + threadIdx.x;
    if (row >= N_PTS) return;

    float acc[64];
    #pragma unroll
    for (int j = 0; j < 64; j++) acc[j] = b2[half * 64 + j];

    const float4* zr = (const float4*)(z1 + (size_t)row * CMID);
    #pragma unroll 2
    for (int c4 = 0; c4 < CMID / 4; c4++) {
        float4 zf = zr[c4];
        int c = c4 * 4;
        float h0 = fmaxf(fmaf(zf.x, Al[c + 0], Bl[c + 0]), 0.f);
        float h1 = fmaxf(fmaf(zf.y, Al[c + 1], Bl[c + 1]), 0.f);
        float h2 = fmaxf(fmaf(zf.z, Al[c + 2], Bl[c + 2]), 0.f);
        float h3 = fmaxf(fmaf(zf.w, Al[c + 3], Bl[c + 3]), 0.f);
        const float* wr = Wl + c * 64;
        #pragma unroll
        for (int j = 0; j < 64; j++) acc[j] = fmaf(h0, wr[j], acc[j]);
        #pragma unroll
        for (int j = 0; j < 64; j++) acc[j] = fmaf(h1, wr[64 + j], acc[j]);
        #pragma unroll
        for (int j = 0; j < 64; j++) acc[j] = fmaf(h2, wr[128 + j], acc[j]);
        #pragma unroll
        for (int j = 0; j < 64; j++) acc[j] = fmaf(h3, wr[192 + j], acc[j]);
    }
    float4* zo = (float4*)(z2 + (size_t)row * COUT + half * 64);
    #pragma unroll
    for (int j = 0; j < 16; j++)
        zo[j] = make_float4(acc[4 * j], acc[4 * j + 1], acc[4 * j + 2], acc[4 * j + 3]);
}

// ---- 7. h2 = bf16(relu(z2*A2+B2)) ; fin2 fused into prologue ----
__global__ __launch_bounds__(256) void h2_k(const float* __restrict__ z2,
                                            const float* __restrict__ S2,
                                            const float* __restrict__ Q2,
                                            const float* __restrict__ g2,
                                            const float* __restrict__ be2,
                                            unsigned short* __restrict__ h2) {
    __shared__ float Al[COUT], Bl[COUT];
    if (threadIdx.x < COUT) {
        const float inv = 1.0f / (float)NK;
        float m = S2[threadIdx.x] * inv;
        float v = Q2[threadIdx.x] * inv - m * m;
        float a = g2[threadIdx.x] * rsqrtf(v + 1e-5f);
        Al[threadIdx.x] = a;
        Bl[threadIdx.x] = be2[threadIdx.x] - m * a;
    }
    __syncthreads();
    int i = blockIdx.x * 256 + threadIdx.x;       // float4-group index over N*128
    if (i >= N_PTS * COUT / 4) return;
    float4 z = ((const float4*)z2)[i];
    int c = (i * 4) & (COUT - 1);
    float h0 = fmaxf(fmaf(z.x, Al[c + 0], Bl[c + 0]), 0.f);
    float h1 = fmaxf(fmaf(z.y, Al[c + 1], Bl[c + 1]), 0.f);
    float h2v = fmaxf(fmaf(z.z, Al[c + 2], Bl[c + 2]), 0.f);
    float h3 = fmaxf(fmaf(z.w, Al[c + 3], Bl[c + 3]), 0.f);
    unsigned lo = (unsigned)f2bf(h0) | ((unsigned)f2bf(h1) << 16);
    unsigned hi = (unsigned)f2bf(h2v) | ((unsigned)f2bf(h3) << 16);
    ((uint2*)h2)[i] = make_uint2(lo, hi);
}

// ---- 8. out[n,c] = max_k h2[idx[n,k],c]   (one wave per point; h2 >= 0 so init 0) ----
__global__ __launch_bounds__(256) void gather_k(const unsigned short* __restrict__ h2,
                                                const int* __restrict__ idx,
                                                float* __restrict__ out) {
    int w = threadIdx.x >> 6;
    int lane = threadIdx.x & 63;
    int n = blockIdx.x * 4 + w;
    if (n >= N_PTS) return;
    const int* ip = idx + n * KNN;
    float m0 = 0.f, m1 = 0.f;
    #pragma unroll
    for (int k = 0; k < KNN; k++) {
        int j = ip[k];
        unsigned v = ((const unsigned*)(h2 + (size_t)j * COUT))[lane];  // 2 packed bf16
        float f0 = __uint_as_float(v << 16);
        float f1 = __uint_as_float(v & 0xffff0000u);
        m0 = fmaxf(m0, f0);
        m1 = fmaxf(m1, f1);
    }
    float2 r; r.x = m0; r.y = m1;
    ((float2*)(out + (size_t)n * COUT))[lane] = r;
}

extern "C" void kernel_launch(void* const* d_in, const int* in_sizes, int n_in,
                              void* d_out, int out_size, void* d_ws, size_t ws_size,
                              hipStream_t stream) {
    const float* feat = (const float*)d_in[0];
    const int*   idx  = (const int*)d_in[1];
    const float* W1   = (const float*)d_in[2];
    const float* b1   = (const float*)d_in[3];
    const float* g1   = (const float*)d_in[4];
    const float* be1  = (const float*)d_in[5];
    const float* W2   = (const float*)d_in[6];
    const float* b2   = (const float*)d_in[7];
    const float* g2   = (const float*)d_in[8];
    const float* be2  = (const float*)d_in[9];
    float* out = (float*)d_out;

    char* ws = (char*)d_ws;
    unsigned short* pc = (unsigned short*)(ws + OFF_Z2);  // aliases z2 head; dead before gemm2
    float* z2     = (float*)(ws + OFF_Z2);
    float* counts = (float*)(ws + OFF_CNT);
    float* S1 = (float*)(ws + OFF_STATS);
    float* Q1 = S1 + 64;
    float* S2 = S1 + 128;
    float* Q2 = S1 + 256;
    float* z1 = (float*)(ws + OFF_Z1);
    unsigned short* h2 = (unsigned short*)(ws + OFF_Z1);  // aliases z1; z1 dead before h2 written

    hipMemsetAsync(ws + OFF_STATS, 0, 1536, stream);

    hist_k<<<4 * HSLC, 256, 0, stream>>>(idx, pc);
    sum_counts_k<<<(N_PTS / 2 + 255) / 256, 256, 0, stream>>>(pc, counts);
    gemm1_k<<<(N_PTS + 255) / 256, 256, 0, stream>>>(feat, W1, b1, z1);
    stats_k<64><<<512, 256, 0, stream>>>(z1, counts, S1, Q1);
    gemm2_k<<<dim3((N_PTS + 255) / 256, 2), 256, 0, stream>>>(z1, S1, Q1, g1, be1, W2, b2, z2);
    stats_k<128><<<512, 256, 0, stream>>>(z2, counts, S2, Q2);
    h2_k<<<N_PTS * COUT / 4 / 256, 256, 0, stream>>>(z2, S2, Q2, g2, be2, h2);
    gather_k<<<N_PTS / 4, 256, 0, stream>>>(h2, idx, out);
}

// Round 4
// 305.271 us; speedup vs baseline: 1.9188x; 1.1042x over previous
//
#include <hip/hip_runtime.h>
#include <hip/hip_bf16.h>

#define N_PTS 100000
#define KNN   16
#define NK    (N_PTS * KNN)
#define CIN   64
#define CMID  64
#define COUT  128

#define HSLC    32           // histogram slices
#define SEG_CNT 25000        // counters per segment (4 segments cover 100k)
#define SEG_U32 12500

// ---------------- ws layout (bytes) ----------------
// [0, 25,600,000)           z2b (N*128 bf16); head first holds pc (32 x 100k ushort
//                           partial counts, 6.4MB) - pc dead before gemm2 writes z2b
// [25,600,000, +12,800,000) z1b (N*64 bf16)
// [38,400,000, +400,000)    counts (float)
// [38,800,000, +1,536)      stats: S1[64] Q1[64] S2[128] Q2[128]  (memset 0)
// [38,801,536, +16,384)     W2bf: W2 pre-swizzled to MFMA B-frag layout (bf16)
#define OFF_Z2B   0
#define OFF_Z1B   25600000
#define OFF_CNT   38400000
#define OFF_STATS 38800000
#define OFF_W2BF  38801536

typedef __attribute__((ext_vector_type(8))) short bf16x8;
typedef __attribute__((ext_vector_type(4))) float f32x4;
union U8 { uint4 u; bf16x8 v; unsigned short s[8]; };

__device__ __forceinline__ unsigned short f2bf(float f) {
    unsigned u = __float_as_uint(f);
    unsigned r = (u + 0x7fffu + ((u >> 16) & 1u)) >> 16;   // RNE
    return (unsigned short)r;
}

// ---- 1. segmented LDS histogram: 4 segments x 32 slices = 128 blocks ----
__global__ __launch_bounds__(256) void hist_k(const int* __restrict__ idx,
                                              unsigned short* __restrict__ pc) {
    __shared__ unsigned int smem[SEG_U32];     // 50 KB
    int seg  = blockIdx.x & 3;
    int slc  = blockIdx.x >> 2;
    int base = seg * SEG_CNT;

    for (int i = threadIdx.x; i < SEG_U32; i += 256) smem[i] = 0;
    __syncthreads();

    const int4* ip = (const int4*)idx;
    const int per = NK / 4 / HSLC;             // 12500 int4 per slice
    int s = slc * per, e = s + per;
    for (int i = s + threadIdx.x; i < e; i += 256) {
        int4 v = ip[i];
        int a;
        a = v.x - base; if ((unsigned)a < (unsigned)SEG_CNT)
            atomicAdd(&smem[a >> 1], 1u << ((a & 1) * 16));
        a = v.y - base; if ((unsigned)a < (unsigned)SEG_CNT)
            atomicAdd(&smem[a >> 1], 1u << ((a & 1) * 16));
        a = v.z - base; if ((unsigned)a < (unsigned)SEG_CNT)
            atomicAdd(&smem[a >> 1], 1u << ((a & 1) * 16));
        a = v.w - base; if ((unsigned)a < (unsigned)SEG_CNT)
            atomicAdd(&smem[a >> 1], 1u << ((a & 1) * 16));
    }
    __syncthreads();

    unsigned int* outp = (unsigned int*)(pc + (size_t)slc * N_PTS) + seg * SEG_U32;
    for (int i = threadIdx.x; i < SEG_U32; i += 256) outp[i] = smem[i];
}

// ---- 2. counts = sum of partials (196 blocks) + W2 frag-swizzle (block 196) ----
__global__ __launch_bounds__(256) void sum_counts_k(const unsigned short* __restrict__ pc,
                                                    float* __restrict__ counts,
                                                    const float* __restrict__ W2,
                                                    unsigned short* __restrict__ w2bf) {
    if (blockIdx.x == 196) {
        // B-frag layout: e = ((nt*2+kh)*64 + lane)*8 + j ; value = bf16(W2[k,n])
        for (int e = threadIdx.x; e < 8192; e += 256) {
            int j    = e & 7;
            int lane = (e >> 3) & 63;
            int kh   = (e >> 9) & 1;
            int nt   = e >> 10;
            int k = kh * 32 + (lane >> 4) * 8 + j;
            int n = nt * 16 + (lane & 15);
            w2bf[e] = f2bf(W2[k * COUT + n]);
        }
        return;
    }
    int i = blockIdx.x * 256 + threadIdx.x;    // uint-pair index over N_PTS/2
    if (i >= N_PTS / 2) return;
    const unsigned int* p = (const unsigned int*)pc;
    unsigned int u = 0;
    #pragma unroll
    for (int s = 0; s < HSLC; s++) u += p[s * (N_PTS / 2) + i];
    float2 r;
    r.x = (float)(u & 0xffffu);
    r.y = (float)(u >> 16);
    ((float2*)counts)[i] = r;
}

// ---- 3. z1b = bf16(feat @ W1 + b1) ----
__global__ __launch_bounds__(256) void gemm1_k(const float* __restrict__ feat,
                                               const float* __restrict__ W1,
                                               const float* __restrict__ b1,
                                               unsigned short* __restrict__ z1b) {
    __shared__ float Wl[CIN * CMID];
    for (int i = threadIdx.x; i < CIN * CMID / 4; i += 256)
        ((float4*)Wl)[i] = ((const float4*)W1)[i];
    __syncthreads();

    int row = blockIdx.x * 256 + threadIdx.x;
    if (row >= N_PTS) return;

    float acc[CMID];
    #pragma unroll
    for (int j = 0; j < CMID; j++) acc[j] = b1[j];

    const float4* fr = (const float4*)(feat + (size_t)row * CIN);
    #pragma unroll 4
    for (int c4 = 0; c4 < CIN / 4; c4++) {
        float4 f = fr[c4];
        const float* wr = Wl + c4 * 4 * CMID;
        #pragma unroll
        for (int j = 0; j < CMID; j++) acc[j] = fmaf(f.x, wr[j], acc[j]);
        #pragma unroll
        for (int j = 0; j < CMID; j++) acc[j] = fmaf(f.y, wr[CMID + j], acc[j]);
        #pragma unroll
        for (int j = 0; j < CMID; j++) acc[j] = fmaf(f.z, wr[2 * CMID + j], acc[j]);
        #pragma unroll
        for (int j = 0; j < CMID; j++) acc[j] = fmaf(f.w, wr[3 * CMID + j], acc[j]);
    }
    uint4* zo = (uint4*)(z1b + (size_t)row * CMID);
    #pragma unroll
    for (int j8 = 0; j8 < 8; j8++) {
        uint4 o;
        o.x = (unsigned)f2bf(acc[8 * j8 + 0]) | ((unsigned)f2bf(acc[8 * j8 + 1]) << 16);
        o.y = (unsigned)f2bf(acc[8 * j8 + 2]) | ((unsigned)f2bf(acc[8 * j8 + 3]) << 16);
        o.z = (unsigned)f2bf(acc[8 * j8 + 4]) | ((unsigned)f2bf(acc[8 * j8 + 5]) << 16);
        o.w = (unsigned)f2bf(acc[8 * j8 + 6]) | ((unsigned)f2bf(acc[8 * j8 + 7]) << 16);
        zo[j8] = o;
    }
}

// ---- 4. stats1: S1[c] += cnt*z1, Q1[c] += cnt*z1^2  (z1 bf16-packed) ----
__global__ __launch_bounds__(256) void stats1_k(const unsigned int* __restrict__ z1u,
                                                const float* __restrict__ counts,
                                                float* __restrict__ S, float* __restrict__ Q) {
    int ucol = threadIdx.x & 31, grp = threadIdx.x >> 5;
    float s0 = 0, q0 = 0, s1 = 0, q1 = 0;
    for (int row = blockIdx.x * 8 + grp; row < N_PTS; row += 256 * 8) {
        float cnt = counts[row];
        unsigned u = z1u[(size_t)row * 32 + ucol];
        float f0 = __uint_as_float(u << 16), f1 = __uint_as_float(u & 0xffff0000u);
        s0 = fmaf(cnt, f0, s0); q0 = fmaf(cnt * f0, f0, q0);
        s1 = fmaf(cnt, f1, s1); q1 = fmaf(cnt * f1, f1, q1);
    }
    __shared__ float sm[4][256];
    sm[0][threadIdx.x] = s0; sm[1][threadIdx.x] = q0;
    sm[2][threadIdx.x] = s1; sm[3][threadIdx.x] = q1;
    __syncthreads();
    if (threadIdx.x < 32) {
        float ts0 = 0, tq0 = 0, ts1 = 0, tq1 = 0;
        #pragma unroll
        for (int g = 0; g < 8; g++) {
            ts0 += sm[0][g * 32 + threadIdx.x]; tq0 += sm[1][g * 32 + threadIdx.x];
            ts1 += sm[2][g * 32 + threadIdx.x]; tq1 += sm[3][g * 32 + threadIdx.x];
        }
        atomicAdd(&S[2 * threadIdx.x], ts0);     atomicAdd(&Q[2 * threadIdx.x], tq0);
        atomicAdd(&S[2 * threadIdx.x + 1], ts1); atomicAdd(&Q[2 * threadIdx.x + 1], tq1);
    }
}

// ---- 5. MFMA gemm2: z2b = bf16( relu(z1*A1+B1) @ W2 + b2 ) ----
__device__ __forceinline__ bf16x8 bnrelu(uint4 r, float4 alo, float4 ahi,
                                         float4 blo, float4 bhi) {
    float z0 = __uint_as_float(r.x << 16), z1 = __uint_as_float(r.x & 0xffff0000u);
    float z2 = __uint_as_float(r.y << 16), z3 = __uint_as_float(r.y & 0xffff0000u);
    float z4 = __uint_as_float(r.z << 16), z5 = __uint_as_float(r.z & 0xffff0000u);
    float z6 = __uint_as_float(r.w << 16), z7 = __uint_as_float(r.w & 0xffff0000u);
    U8 o;
    o.s[0] = f2bf(fmaxf(fmaf(alo.x, z0, blo.x), 0.f));
    o.s[1] = f2bf(fmaxf(fmaf(alo.y, z1, blo.y), 0.f));
    o.s[2] = f2bf(fmaxf(fmaf(alo.z, z2, blo.z), 0.f));
    o.s[3] = f2bf(fmaxf(fmaf(alo.w, z3, blo.w), 0.f));
    o.s[4] = f2bf(fmaxf(fmaf(ahi.x, z4, bhi.x), 0.f));
    o.s[5] = f2bf(fmaxf(fmaf(ahi.y, z5, bhi.y), 0.f));
    o.s[6] = f2bf(fmaxf(fmaf(ahi.z, z6, bhi.z), 0.f));
    o.s[7] = f2bf(fmaxf(fmaf(ahi.w, z7, bhi.w), 0.f));
    return o.v;
}

__global__ __launch_bounds__(256) void gemm2_mfma_k(const unsigned short* __restrict__ z1b,
                                                    const unsigned short* __restrict__ w2bf,
                                                    const float* __restrict__ S1,
                                                    const float* __restrict__ Q1,
                                                    const float* __restrict__ g1,
                                                    const float* __restrict__ be1,
                                                    const float* __restrict__ b2,
                                                    unsigned short* __restrict__ z2b) {
    __shared__ float Al[64], Bl[64];
    if (threadIdx.x < 64) {
        const float inv = 1.0f / (float)NK;
        float m = S1[threadIdx.x] * inv;
        float v = Q1[threadIdx.x] * inv - m * m;
        float a = g1[threadIdx.x] * rsqrtf(v + 1e-5f);
        Al[threadIdx.x] = a;
        Bl[threadIdx.x] = be1[threadIdx.x] - m * a;
    }
    __syncthreads();

    int lane = threadIdx.x & 63;
    int il = lane & 15, quad = lane >> 4;

    float4 a0lo = *(const float4*)(Al + quad * 8);
    float4 a0hi = *(const float4*)(Al + quad * 8 + 4);
    float4 b0lo = *(const float4*)(Bl + quad * 8);
    float4 b0hi = *(const float4*)(Bl + quad * 8 + 4);
    float4 a1lo = *(const float4*)(Al + 32 + quad * 8);
    float4 a1hi = *(const float4*)(Al + 32 + quad * 8 + 4);
    float4 b1lo = *(const float4*)(Bl + 32 + quad * 8);
    float4 b1hi = *(const float4*)(Bl + 32 + quad * 8 + 4);

    // B-frags: resident in registers for the whole kernel
    bf16x8 bfr[8][2];
    const uint4* wp = (const uint4*)w2bf;
    #pragma unroll
    for (int nt = 0; nt < 8; nt++) {
        U8 t0; t0.u = wp[(nt * 2 + 0) * 64 + lane]; bfr[nt][0] = t0.v;
        U8 t1; t1.u = wp[(nt * 2 + 1) * 64 + lane]; bfr[nt][1] = t1.v;
    }
    float bias[8];
    #pragma unroll
    for (int nt = 0; nt < 8; nt++) bias[nt] = b2[nt * 16 + il];

    int wid = (blockIdx.x * 256 + threadIdx.x) >> 6;
    const int nwaves = gridDim.x * 4;
    for (int tile = wid; tile < N_PTS / 16; tile += nwaves) {
        int m0 = tile * 16;
        const uint4* ar = (const uint4*)(z1b + (size_t)(m0 + il) * 64);
        uint4 ra0 = ar[quad];         // k = quad*8 .. +7
        uint4 ra1 = ar[4 + quad];     // k = 32 + quad*8 .. +7
        bf16x8 af0 = bnrelu(ra0, a0lo, a0hi, b0lo, b0hi);
        bf16x8 af1 = bnrelu(ra1, a1lo, a1hi, b1lo, b1hi);
        #pragma unroll
        for (int nt = 0; nt < 8; nt++) {
            f32x4 acc = {bias[nt], bias[nt], bias[nt], bias[nt]};
            acc = __builtin_amdgcn_mfma_f32_16x16x32_bf16(af0, bfr[nt][0], acc, 0, 0, 0);
            acc = __builtin_amdgcn_mfma_f32_16x16x32_bf16(af1, bfr[nt][1], acc, 0, 0, 0);
            // C/D: col = lane&15, row = quad*4 + reg
            unsigned short* zp = z2b + (size_t)(m0 + quad * 4) * COUT + nt * 16 + il;
            zp[0]       = f2bf(acc[0]);
            zp[COUT]    = f2bf(acc[1]);
            zp[2 * COUT] = f2bf(acc[2]);
            zp[3 * COUT] = f2bf(acc[3]);
        }
    }
}

// ---- 6. stats2 over z2b (128 ch = 64 packed uints/row) ----
__global__ __launch_bounds__(256) void stats2_k(const unsigned int* __restrict__ z2u,
                                                const float* __restrict__ counts,
                                                float* __restrict__ S, float* __restrict__ Q) {
    int ucol = threadIdx.x & 63, grp = threadIdx.x >> 6;
    float s0 = 0, q0 = 0, s1 = 0, q1 = 0;
    for (int row = blockIdx.x * 4 + grp; row < N_PTS; row += gridDim.x * 4) {
        float cnt = counts[row];
        unsigned u = z2u[(size_t)row * 64 + ucol];
        float f0 = __uint_as_float(u << 16), f1 = __uint_as_float(u & 0xffff0000u);
        s0 = fmaf(cnt, f0, s0); q0 = fmaf(cnt * f0, f0, q0);
        s1 = fmaf(cnt, f1, s1); q1 = fmaf(cnt * f1, f1, q1);
    }
    __shared__ float sm[4][256];
    sm[0][threadIdx.x] = s0; sm[1][threadIdx.x] = q0;
    sm[2][threadIdx.x] = s1; sm[3][threadIdx.x] = q1;
    __syncthreads();
    if (threadIdx.x < 64) {
        float ts0 = 0, tq0 = 0, ts1 = 0, tq1 = 0;
        #pragma unroll
        for (int g = 0; g < 4; g++) {
            ts0 += sm[0][g * 64 + threadIdx.x]; tq0 += sm[1][g * 64 + threadIdx.x];
            ts1 += sm[2][g * 64 + threadIdx.x]; tq1 += sm[3][g * 64 + threadIdx.x];
        }
        atomicAdd(&S[2 * threadIdx.x], ts0);     atomicAdd(&Q[2 * threadIdx.x], tq0);
        atomicAdd(&S[2 * threadIdx.x + 1], ts1); atomicAdd(&Q[2 * threadIdx.x + 1], tq1);
    }
}

// ---- 7. gather + fused BN2/relu/max: out[n,c] = relu(max_k(a*z2[idx,c]+b)) ----
__global__ __launch_bounds__(256) void gather_k(const unsigned int* __restrict__ z2u,
                                                const int* __restrict__ idx,
                                                const float* __restrict__ S2,
                                                const float* __restrict__ Q2,
                                                const float* __restrict__ g2,
                                                const float* __restrict__ be2,
                                                float* __restrict__ out) {
    int w = threadIdx.x >> 6;
    int lane = threadIdx.x & 63;
    int n = blockIdx.x * 4 + w;

    const float inv = 1.0f / (float)NK;
    float2 Sv = ((const float2*)S2)[lane];
    float2 Qv = ((const float2*)Q2)[lane];
    float2 gv = ((const float2*)g2)[lane];
    float2 bv = ((const float2*)be2)[lane];
    float m0c = Sv.x * inv, m1c = Sv.y * inv;
    float a0 = gv.x * rsqrtf(Qv.x * inv - m0c * m0c + 1e-5f);
    float a1 = gv.y * rsqrtf(Qv.y * inv - m1c * m1c + 1e-5f);
    float b0 = bv.x - m0c * a0;
    float b1 = bv.y - m1c * a1;

    const int* ip = idx + n * KNN;
    float mx0 = -1e30f, mn0 = 1e30f, mx1 = -1e30f, mn1 = 1e30f;
    #pragma unroll
    for (int k = 0; k < KNN; k++) {
        int j = ip[k];
        unsigned v = z2u[(size_t)j * 64 + lane];
        float f0 = __uint_as_float(v << 16);
        float f1 = __uint_as_float(v & 0xffff0000u);
        mx0 = fmaxf(mx0, f0); mn0 = fminf(mn0, f0);
        mx1 = fmaxf(mx1, f1); mn1 = fminf(mn1, f1);
    }
    float2 r;
    r.x = fmaxf(fmaxf(fmaf(a0, mx0, b0), fmaf(a0, mn0, b0)), 0.f);
    r.y = fmaxf(fmaxf(fmaf(a1, mx1, b1), fmaf(a1, mn1, b1)), 0.f);
    ((float2*)(out + (size_t)n * COUT))[lane] = r;
}

extern "C" void kernel_launch(void* const* d_in, const int* in_sizes, int n_in,
                              void* d_out, int out_size, void* d_ws, size_t ws_size,
                              hipStream_t stream) {
    const float* feat = (const float*)d_in[0];
    const int*   idx  = (const int*)d_in[1];
    const float* W1   = (const float*)d_in[2];
    const float* b1   = (const float*)d_in[3];
    const float* g1   = (const float*)d_in[4];
    const float* be1  = (const float*)d_in[5];
    const float* W2   = (const float*)d_in[6];
    const float* b2   = (const float*)d_in[7];
    const float* g2   = (const float*)d_in[8];
    const float* be2  = (const float*)d_in[9];
    float* out = (float*)d_out;

    char* ws = (char*)d_ws;
    unsigned short* z2b = (unsigned short*)(ws + OFF_Z2B);
    unsigned short* pc  = (unsigned short*)(ws + OFF_Z2B);   // alias, dead before gemm2
    unsigned short* z1b = (unsigned short*)(ws + OFF_Z1B);
    float* counts = (float*)(ws + OFF_CNT);
    float* S1 = (float*)(ws + OFF_STATS);
    float* Q1 = S1 + 64;
    float* S2 = S1 + 128;
    float* Q2 = S1 + 256;
    unsigned short* w2bf = (unsigned short*)(ws + OFF_W2BF);

    hipMemsetAsync(ws + OFF_STATS, 0, 1536, stream);

    hist_k<<<4 * HSLC, 256, 0, stream>>>(idx, pc);
    sum_counts_k<<<197, 256, 0, stream>>>(pc, counts, W2, w2bf);
    gemm1_k<<<(N_PTS + 255) / 256, 256, 0, stream>>>(feat, W1, b1, z1b);
    stats1_k<<<256, 256, 0, stream>>>((const unsigned int*)z1b, counts, S1, Q1);
    gemm2_mfma_k<<<512, 256, 0, stream>>>(z1b, w2bf, S1, Q1, g1, be1, b2, z2b);
    stats2_k<<<128, 256, 0, stream>>>((const unsigned int*)z2b, counts, S2, Q2);
    gather_k<<<N_PTS / 4, 256, 0, stream>>>((const unsigned int*)z2b, idx, S2, Q2, g2, be2, out);
}

// Round 5
// 242.694 us; speedup vs baseline: 2.4135x; 1.2578x over previous
//
#include <hip/hip_runtime.h>
#include <hip/hip_bf16.h>

#define N_PTS 100000
#define KNN   16
#define NK    (N_PTS * KNN)
#define CIN   64
#define CMID  64
#define COUT  128

#define HSLC    32           // histogram slices
#define SEG_CNT 25000        // counters per segment (4 segments cover 100k)
#define SEG_U32 12500

// ---------------- ws layout (bytes) ----------------
// [0, 25,600,000)           z2b (N*128 bf16); head first holds pc (32 x 100k ushort
//                           partial counts, 6.4MB) - pc dead before gemm2 writes z2b
// [25,600,000, +12,800,000) z1b (N*64 bf16)
// [38,400,000, +400,000)    counts (float)
// [38,800,000, +1,536)      stats: S1[64] Q1[64] S2[128] Q2[128]  (memset 0)
// [38,801,536, +16,384)     W2bf: W2 pre-swizzled to MFMA B-frag layout (bf16)
#define OFF_Z2B   0
#define OFF_Z1B   25600000
#define OFF_CNT   38400000
#define OFF_STATS 38800000
#define OFF_W2BF  38801536

typedef __attribute__((ext_vector_type(8))) short bf16x8;
typedef __attribute__((ext_vector_type(4))) float f32x4;
union U8 { uint4 u; bf16x8 v; unsigned short s[8]; };

__device__ __forceinline__ unsigned short f2bf(float f) {
    unsigned u = __float_as_uint(f);
    unsigned r = (u + 0x7fffu + ((u >> 16) & 1u)) >> 16;   // RNE
    return (unsigned short)r;
}

// ---- 1. segmented LDS histogram: 4 segments x 32 slices = 128 blocks ----
__global__ __launch_bounds__(256) void hist_k(const int* __restrict__ idx,
                                              unsigned short* __restrict__ pc) {
    __shared__ unsigned int smem[SEG_U32];     // 50 KB
    int seg  = blockIdx.x & 3;
    int slc  = blockIdx.x >> 2;
    int base = seg * SEG_CNT;

    for (int i = threadIdx.x; i < SEG_U32; i += 256) smem[i] = 0;
    __syncthreads();

    const int4* ip = (const int4*)idx;
    const int per = NK / 4 / HSLC;             // 12500 int4 per slice
    int s = slc * per, e = s + per;
    for (int i = s + threadIdx.x; i < e; i += 256) {
        int4 v = ip[i];
        int a;
        a = v.x - base; if ((unsigned)a < (unsigned)SEG_CNT)
            atomicAdd(&smem[a >> 1], 1u << ((a & 1) * 16));
        a = v.y - base; if ((unsigned)a < (unsigned)SEG_CNT)
            atomicAdd(&smem[a >> 1], 1u << ((a & 1) * 16));
        a = v.z - base; if ((unsigned)a < (unsigned)SEG_CNT)
            atomicAdd(&smem[a >> 1], 1u << ((a & 1) * 16));
        a = v.w - base; if ((unsigned)a < (unsigned)SEG_CNT)
            atomicAdd(&smem[a >> 1], 1u << ((a & 1) * 16));
    }
    __syncthreads();

    unsigned int* outp = (unsigned int*)(pc + (size_t)slc * N_PTS) + seg * SEG_U32;
    for (int i = threadIdx.x; i < SEG_U32; i += 256) outp[i] = smem[i];
}

// ---- 2. counts = sum of partials (196 blocks) + W2 frag-swizzle (block 196) ----
__global__ __launch_bounds__(256) void sum_counts_k(const unsigned short* __restrict__ pc,
                                                    float* __restrict__ counts,
                                                    const float* __restrict__ W2,
                                                    unsigned short* __restrict__ w2bf) {
    if (blockIdx.x == 196) {
        // B-frag layout: e = ((nt*2+kh)*64 + lane)*8 + j ; value = bf16(W2[k,n])
        for (int e = threadIdx.x; e < 8192; e += 256) {
            int j    = e & 7;
            int lane = (e >> 3) & 63;
            int kh   = (e >> 9) & 1;
            int nt   = e >> 10;
            int k = kh * 32 + (lane >> 4) * 8 + j;
            int n = nt * 16 + (lane & 15);
            w2bf[e] = f2bf(W2[k * COUT + n]);
        }
        return;
    }
    int i = blockIdx.x * 256 + threadIdx.x;    // uint-pair index over N_PTS/2
    if (i >= N_PTS / 2) return;
    const unsigned int* p = (const unsigned int*)pc;
    unsigned int u = 0;
    #pragma unroll
    for (int s = 0; s < HSLC; s++) u += p[s * (N_PTS / 2) + i];
    float2 r;
    r.x = (float)(u & 0xffffu);
    r.y = (float)(u >> 16);
    ((float2*)counts)[i] = r;
}

// ---- 3. z1b = bf16(feat @ W1 + b1) ----
__global__ __launch_bounds__(256) void gemm1_k(const float* __restrict__ feat,
                                               const float* __restrict__ W1,
                                               const float* __restrict__ b1,
                                               unsigned short* __restrict__ z1b) {
    __shared__ float Wl[CIN * CMID];
    for (int i = threadIdx.x; i < CIN * CMID / 4; i += 256)
        ((float4*)Wl)[i] = ((const float4*)W1)[i];
    __syncthreads();

    int row = blockIdx.x * 256 + threadIdx.x;
    if (row >= N_PTS) return;

    float acc[CMID];
    #pragma unroll
    for (int j = 0; j < CMID; j++) acc[j] = b1[j];

    const float4* fr = (const float4*)(feat + (size_t)row * CIN);
    #pragma unroll 4
    for (int c4 = 0; c4 < CIN / 4; c4++) {
        float4 f = fr[c4];
        const float* wr = Wl + c4 * 4 * CMID;
        #pragma unroll
        for (int j = 0; j < CMID; j++) acc[j] = fmaf(f.x, wr[j], acc[j]);
        #pragma unroll
        for (int j = 0; j < CMID; j++) acc[j] = fmaf(f.y, wr[CMID + j], acc[j]);
        #pragma unroll
        for (int j = 0; j < CMID; j++) acc[j] = fmaf(f.z, wr[2 * CMID + j], acc[j]);
        #pragma unroll
        for (int j = 0; j < CMID; j++) acc[j] = fmaf(f.w, wr[3 * CMID + j], acc[j]);
    }
    uint4* zo = (uint4*)(z1b + (size_t)row * CMID);
    #pragma unroll
    for (int j8 = 0; j8 < 8; j8++) {
        uint4 o;
        o.x = (unsigned)f2bf(acc[8 * j8 + 0]) | ((unsigned)f2bf(acc[8 * j8 + 1]) << 16);
        o.y = (unsigned)f2bf(acc[8 * j8 + 2]) | ((unsigned)f2bf(acc[8 * j8 + 3]) << 16);
        o.z = (unsigned)f2bf(acc[8 * j8 + 4]) | ((unsigned)f2bf(acc[8 * j8 + 5]) << 16);
        o.w = (unsigned)f2bf(acc[8 * j8 + 6]) | ((unsigned)f2bf(acc[8 * j8 + 7]) << 16);
        zo[j8] = o;
    }
}

// ---- 4. stats1: throughput version. 8 rows x 8 uint4 per wave, uint4 loads ----
__global__ __launch_bounds__(256) void stats1_k(const uint4* __restrict__ z1q,
                                                const float* __restrict__ counts,
                                                float* __restrict__ S, float* __restrict__ Q) {
    int lane = threadIdx.x & 63, wid = threadIdx.x >> 6;
    int u4c = lane & 7;          // which uint4 of the row (channels u4c*8..+7)
    int r   = lane >> 3;         // row offset 0..7
    float s[8], q[8];
    #pragma unroll
    for (int j = 0; j < 8; j++) { s[j] = 0.f; q[j] = 0.f; }

    for (int rb = blockIdx.x * 32 + wid * 8; rb < N_PTS; rb += gridDim.x * 32) {
        int row = rb + r;                       // N_PTS % 8 == 0, rb % 8 == 0 -> in bounds
        float cnt = counts[row];
        uint4 u = z1q[(size_t)row * 8 + u4c];
        unsigned uu[4] = {u.x, u.y, u.z, u.w};
        #pragma unroll
        for (int p = 0; p < 4; p++) {
            float f0 = __uint_as_float(uu[p] << 16);
            float f1 = __uint_as_float(uu[p] & 0xffff0000u);
            s[2 * p]     = fmaf(cnt, f0, s[2 * p]);
            q[2 * p]     = fmaf(cnt * f0, f0, q[2 * p]);
            s[2 * p + 1] = fmaf(cnt, f1, s[2 * p + 1]);
            q[2 * p + 1] = fmaf(cnt * f1, f1, q[2 * p + 1]);
        }
    }
    // butterfly over row bits (lane bits 3,4,5)
    #pragma unroll
    for (int m = 8; m <= 32; m <<= 1) {
        #pragma unroll
        for (int j = 0; j < 8; j++) {
            s[j] += __shfl_xor(s[j], m, 64);
            q[j] += __shfl_xor(q[j], m, 64);
        }
    }
    __shared__ float sm[4][8][16];
    if (r == 0) {
        #pragma unroll
        for (int j = 0; j < 8; j++) { sm[wid][u4c][j] = s[j]; sm[wid][u4c][8 + j] = q[j]; }
    }
    __syncthreads();
    if (threadIdx.x < 128) {
        int uc = threadIdx.x >> 4, v = threadIdx.x & 15;
        float t = sm[0][uc][v] + sm[1][uc][v] + sm[2][uc][v] + sm[3][uc][v];
        if (v < 8) atomicAdd(&S[uc * 8 + v], t);
        else       atomicAdd(&Q[uc * 8 + v - 8], t);
    }
}

// ---- 5. MFMA gemm2: z2b = bf16( relu(z1*A1+B1) @ W2 + b2 ) ----
__device__ __forceinline__ bf16x8 bnrelu(uint4 r, float4 alo, float4 ahi,
                                         float4 blo, float4 bhi) {
    float z0 = __uint_as_float(r.x << 16), z1 = __uint_as_float(r.x & 0xffff0000u);
    float z2 = __uint_as_float(r.y << 16), z3 = __uint_as_float(r.y & 0xffff0000u);
    float z4 = __uint_as_float(r.z << 16), z5 = __uint_as_float(r.z & 0xffff0000u);
    float z6 = __uint_as_float(r.w << 16), z7 = __uint_as_float(r.w & 0xffff0000u);
    U8 o;
    o.s[0] = f2bf(fmaxf(fmaf(alo.x, z0, blo.x), 0.f));
    o.s[1] = f2bf(fmaxf(fmaf(alo.y, z1, blo.y), 0.f));
    o.s[2] = f2bf(fmaxf(fmaf(alo.z, z2, blo.z), 0.f));
    o.s[3] = f2bf(fmaxf(fmaf(alo.w, z3, blo.w), 0.f));
    o.s[4] = f2bf(fmaxf(fmaf(ahi.x, z4, bhi.x), 0.f));
    o.s[5] = f2bf(fmaxf(fmaf(ahi.y, z5, bhi.y), 0.f));
    o.s[6] = f2bf(fmaxf(fmaf(ahi.z, z6, bhi.z), 0.f));
    o.s[7] = f2bf(fmaxf(fmaf(ahi.w, z7, bhi.w), 0.f));
    return o.v;
}

__global__ __launch_bounds__(256) void gemm2_mfma_k(const unsigned short* __restrict__ z1b,
                                                    const unsigned short* __restrict__ w2bf,
                                                    const float* __restrict__ S1,
                                                    const float* __restrict__ Q1,
                                                    const float* __restrict__ g1,
                                                    const float* __restrict__ be1,
                                                    const float* __restrict__ b2,
                                                    unsigned short* __restrict__ z2b) {
    __shared__ float Al[64], Bl[64];
    if (threadIdx.x < 64) {
        const float inv = 1.0f / (float)NK;
        float m = S1[threadIdx.x] * inv;
        float v = Q1[threadIdx.x] * inv - m * m;
        float a = g1[threadIdx.x] * rsqrtf(v + 1e-5f);
        Al[threadIdx.x] = a;
        Bl[threadIdx.x] = be1[threadIdx.x] - m * a;
    }
    __syncthreads();

    int lane = threadIdx.x & 63;
    int il = lane & 15, quad = lane >> 4;

    float4 a0lo = *(const float4*)(Al + quad * 8);
    float4 a0hi = *(const float4*)(Al + quad * 8 + 4);
    float4 b0lo = *(const float4*)(Bl + quad * 8);
    float4 b0hi = *(const float4*)(Bl + quad * 8 + 4);
    float4 a1lo = *(const float4*)(Al + 32 + quad * 8);
    float4 a1hi = *(const float4*)(Al + 32 + quad * 8 + 4);
    float4 b1lo = *(const float4*)(Bl + 32 + quad * 8);
    float4 b1hi = *(const float4*)(Bl + 32 + quad * 8 + 4);

    bf16x8 bfr[8][2];
    const uint4* wp = (const uint4*)w2bf;
    #pragma unroll
    for (int nt = 0; nt < 8; nt++) {
        U8 t0; t0.u = wp[(nt * 2 + 0) * 64 + lane]; bfr[nt][0] = t0.v;
        U8 t1; t1.u = wp[(nt * 2 + 1) * 64 + lane]; bfr[nt][1] = t1.v;
    }
    float bias[8];
    #pragma unroll
    for (int nt = 0; nt < 8; nt++) bias[nt] = b2[nt * 16 + il];

    int wid = (blockIdx.x * 256 + threadIdx.x) >> 6;
    const int nwaves = gridDim.x * 4;
    for (int tile = wid; tile < N_PTS / 16; tile += nwaves) {
        int m0 = tile * 16;
        const uint4* ar = (const uint4*)(z1b + (size_t)(m0 + il) * 64);
        uint4 ra0 = ar[quad];
        uint4 ra1 = ar[4 + quad];
        bf16x8 af0 = bnrelu(ra0, a0lo, a0hi, b0lo, b0hi);
        bf16x8 af1 = bnrelu(ra1, a1lo, a1hi, b1lo, b1hi);
        #pragma unroll
        for (int nt = 0; nt < 8; nt++) {
            f32x4 acc = {bias[nt], bias[nt], bias[nt], bias[nt]};
            acc = __builtin_amdgcn_mfma_f32_16x16x32_bf16(af0, bfr[nt][0], acc, 0, 0, 0);
            acc = __builtin_amdgcn_mfma_f32_16x16x32_bf16(af1, bfr[nt][1], acc, 0, 0, 0);
            unsigned short* zp = z2b + (size_t)(m0 + quad * 4) * COUT + nt * 16 + il;
            zp[0]        = f2bf(acc[0]);
            zp[COUT]     = f2bf(acc[1]);
            zp[2 * COUT] = f2bf(acc[2]);
            zp[3 * COUT] = f2bf(acc[3]);
        }
    }
}

// ---- 6. stats2: throughput version. 4 rows x 16 uint4 per wave ----
__global__ __launch_bounds__(256) void stats2_k(const uint4* __restrict__ z2q,
                                                const float* __restrict__ counts,
                                                float* __restrict__ S, float* __restrict__ Q) {
    int lane = threadIdx.x & 63, wid = threadIdx.x >> 6;
    int u4c = lane & 15;         // which uint4 of the row (channels u4c*8..+7)
    int r   = lane >> 4;         // row offset 0..3
    float s[8], q[8];
    #pragma unroll
    for (int j = 0; j < 8; j++) { s[j] = 0.f; q[j] = 0.f; }

    for (int rb = blockIdx.x * 16 + wid * 4; rb < N_PTS; rb += gridDim.x * 16) {
        int row = rb + r;                       // N_PTS % 4 == 0 -> in bounds
        float cnt = counts[row];
        uint4 u = z2q[(size_t)row * 16 + u4c];
        unsigned uu[4] = {u.x, u.y, u.z, u.w};
        #pragma unroll
        for (int p = 0; p < 4; p++) {
            float f0 = __uint_as_float(uu[p] << 16);
            float f1 = __uint_as_float(uu[p] & 0xffff0000u);
            s[2 * p]     = fmaf(cnt, f0, s[2 * p]);
            q[2 * p]     = fmaf(cnt * f0, f0, q[2 * p]);
            s[2 * p + 1] = fmaf(cnt, f1, s[2 * p + 1]);
            q[2 * p + 1] = fmaf(cnt * f1, f1, q[2 * p + 1]);
        }
    }
    // butterfly over row bits (lane bits 4,5)
    #pragma unroll
    for (int m = 16; m <= 32; m <<= 1) {
        #pragma unroll
        for (int j = 0; j < 8; j++) {
            s[j] += __shfl_xor(s[j], m, 64);
            q[j] += __shfl_xor(q[j], m, 64);
        }
    }
    __shared__ float sm[4][16][16];
    if (r == 0) {
        #pragma unroll
        for (int j = 0; j < 8; j++) { sm[wid][u4c][j] = s[j]; sm[wid][u4c][8 + j] = q[j]; }
    }
    __syncthreads();
    {
        int uc = threadIdx.x >> 4, v = threadIdx.x & 15;
        float t = sm[0][uc][v] + sm[1][uc][v] + sm[2][uc][v] + sm[3][uc][v];
        if (v < 8) atomicAdd(&S[uc * 8 + v], t);
        else       atomicAdd(&Q[uc * 8 + v - 8], t);
    }
}

// ---- 7. gather + fused BN2/relu/max: out[n,c] = relu(max_k(a*z2[idx,c]+b)) ----
__global__ __launch_bounds__(256) void gather_k(const unsigned int* __restrict__ z2u,
                                                const int* __restrict__ idx,
                                                const float* __restrict__ S2,
                                                const float* __restrict__ Q2,
                                                const float* __restrict__ g2,
                                                const float* __restrict__ be2,
                                                float* __restrict__ out) {
    int w = threadIdx.x >> 6;
    int lane = threadIdx.x & 63;
    int n = blockIdx.x * 4 + w;

    const float inv = 1.0f / (float)NK;
    float2 Sv = ((const float2*)S2)[lane];
    float2 Qv = ((const float2*)Q2)[lane];
    float2 gv = ((const float2*)g2)[lane];
    float2 bv = ((const float2*)be2)[lane];
    float m0c = Sv.x * inv, m1c = Sv.y * inv;
    float a0 = gv.x * rsqrtf(Qv.x * inv - m0c * m0c + 1e-5f);
    float a1 = gv.y * rsqrtf(Qv.y * inv - m1c * m1c + 1e-5f);
    float b0 = bv.x - m0c * a0;
    float b1 = bv.y - m1c * a1;

    const int* ip = idx + n * KNN;
    float mx0 = -1e30f, mn0 = 1e30f, mx1 = -1e30f, mn1 = 1e30f;
    #pragma unroll
    for (int k = 0; k < KNN; k++) {
        int j = ip[k];
        unsigned v = z2u[(size_t)j * 64 + lane];
        float f0 = __uint_as_float(v << 16);
        float f1 = __uint_as_float(v & 0xffff0000u);
        mx0 = fmaxf(mx0, f0); mn0 = fminf(mn0, f0);
        mx1 = fmaxf(mx1, f1); mn1 = fminf(mn1, f1);
    }
    float2 r;
    r.x = fmaxf(fmaxf(fmaf(a0, mx0, b0), fmaf(a0, mn0, b0)), 0.f);
    r.y = fmaxf(fmaxf(fmaf(a1, mx1, b1), fmaf(a1, mn1, b1)), 0.f);
    ((float2*)(out + (size_t)n * COUT))[lane] = r;
}

extern "C" void kernel_launch(void* const* d_in, const int* in_sizes, int n_in,
                              void* d_out, int out_size, void* d_ws, size_t ws_size,
                              hipStream_t stream) {
    const float* feat = (const float*)d_in[0];
    const int*   idx  = (const int*)d_in[1];
    const float* W1   = (const float*)d_in[2];
    const float* b1   = (const float*)d_in[3];
    const float* g1   = (const float*)d_in[4];
    const float* be1  = (const float*)d_in[5];
    const float* W2   = (const float*)d_in[6];
    const float* b2   = (const float*)d_in[7];
    const float* g2   = (const float*)d_in[8];
    const float* be2  = (const float*)d_in[9];
    float* out = (float*)d_out;

    char* ws = (char*)d_ws;
    unsigned short* z2b = (unsigned short*)(ws + OFF_Z2B);
    unsigned short* pc  = (unsigned short*)(ws + OFF_Z2B);   // alias, dead before gemm2
    unsigned short* z1b = (unsigned short*)(ws + OFF_Z1B);
    float* counts = (float*)(ws + OFF_CNT);
    float* S1 = (float*)(ws + OFF_STATS);
    float* Q1 = S1 + 64;
    float* S2 = S1 + 128;
    float* Q2 = S1 + 256;
    unsigned short* w2bf = (unsigned short*)(ws + OFF_W2BF);

    hipMemsetAsync(ws + OFF_STATS, 0, 1536, stream);

    hist_k<<<4 * HSLC, 256, 0, stream>>>(idx, pc);
    sum_counts_k<<<197, 256, 0, stream>>>(pc, counts, W2, w2bf);
    gemm1_k<<<(N_PTS + 255) / 256, 256, 0, stream>>>(feat, W1, b1, z1b);
    stats1_k<<<256, 256, 0, stream>>>((const uint4*)z1b, counts, S1, Q1);
    gemm2_mfma_k<<<512, 256, 0, stream>>>(z1b, w2bf, S1, Q1, g1, be1, b2, z2b);
    stats2_k<<<256, 256, 0, stream>>>((const uint4*)z2b, counts, S2, Q2);
    gather_k<<<N_PTS / 4, 256, 0, stream>>>((const unsigned int*)z2b, idx, S2, Q2, g2, be2, out);
}

// Round 6
// 206.812 us; speedup vs baseline: 2.8323x; 1.1735x over previous
//
#include <hip/hip_runtime.h>
#include <hip/hip_bf16.h>

#define N_PTS 100000
#define KNN   16
#define NK    (N_PTS * KNN)
#define CIN   64
#define CMID  64
#define COUT  128

#define HSLC    64           // histogram slices
#define SEG_CNT 25000        // counters per segment (4 segments cover 100k)
#define SEG_U32 12500

// ---------------- ws layout (bytes) ----------------
// [0, 25,600,000)           z2b: [2][N][64] bf16 (channel-halved rows, 128 B each);
//                           head first holds pc (64 x 100k ushort partials, 12.8MB)
//                           - pc dead before gemm2 writes z2b
// [25,600,000, +12,800,000) z1b (N*64 bf16, row-major)
// [38,400,000, +400,000)    counts (float)
// [38,800,000, +1,536)      stats: S1[64] Q1[64] S2[128] Q2[128]  (memset 0)
// [38,801,536, +16,384)     W2bf: B-frag-swizzled W2 (bf16)
// [38,817,920, +8,192)      W1bf: B-frag-swizzled W1 (bf16)
#define OFF_Z2B   0
#define OFF_Z1B   25600000
#define OFF_CNT   38400000
#define OFF_STATS 38800000
#define OFF_W2BF  38801536
#define OFF_W1BF  38817920

typedef __attribute__((ext_vector_type(8))) short bf16x8;
typedef __attribute__((ext_vector_type(4))) float f32x4;
union U8 { uint4 u; bf16x8 v; unsigned short s[8]; };

__device__ __forceinline__ unsigned short f2bf(float f) {
    unsigned u = __float_as_uint(f);
    unsigned r = (u + 0x7fffu + ((u >> 16) & 1u)) >> 16;   // RNE
    return (unsigned short)r;
}

// ---- 1. segmented LDS histogram: 4 segments x 64 slices = 256 blocks ----
__global__ __launch_bounds__(256) void hist_k(const int* __restrict__ idx,
                                              unsigned short* __restrict__ pc) {
    __shared__ unsigned int smem[SEG_U32];     // 50 KB
    int seg  = blockIdx.x & 3;
    int slc  = blockIdx.x >> 2;                // 0..63
    int base = seg * SEG_CNT;

    for (int i = threadIdx.x; i < SEG_U32; i += 256) smem[i] = 0;
    __syncthreads();

    const int4* ip = (const int4*)idx;
    const int per = NK / 4 / HSLC;             // 6250 int4 per slice
    int s = slc * per, e = s + per;
    for (int i = s + threadIdx.x; i < e; i += 256) {
        int4 v = ip[i];
        int a;
        a = v.x - base; if ((unsigned)a < (unsigned)SEG_CNT)
            atomicAdd(&smem[a >> 1], 1u << ((a & 1) * 16));
        a = v.y - base; if ((unsigned)a < (unsigned)SEG_CNT)
            atomicAdd(&smem[a >> 1], 1u << ((a & 1) * 16));
        a = v.z - base; if ((unsigned)a < (unsigned)SEG_CNT)
            atomicAdd(&smem[a >> 1], 1u << ((a & 1) * 16));
        a = v.w - base; if ((unsigned)a < (unsigned)SEG_CNT)
            atomicAdd(&smem[a >> 1], 1u << ((a & 1) * 16));
    }
    __syncthreads();

    unsigned int* outp = (unsigned int*)(pc + (size_t)slc * N_PTS) + seg * SEG_U32;
    for (int i = threadIdx.x; i < SEG_U32; i += 256) outp[i] = smem[i];
}

// ---- 2. counts = sum of 64 partials; blocks 196/197 swizzle W2/W1 to B-frag layout ----
__global__ __launch_bounds__(256) void sum_counts_k(const unsigned short* __restrict__ pc,
                                                    float* __restrict__ counts,
                                                    const float* __restrict__ W2,
                                                    unsigned short* __restrict__ w2bf,
                                                    const float* __restrict__ W1,
                                                    unsigned short* __restrict__ w1bf) {
    if (blockIdx.x == 196) {
        // B-frag: e = ((nt*2+kh)*64 + lane)*8 + j ; value = bf16(W2[k,n])
        for (int e = threadIdx.x; e < 8192; e += 256) {
            int j = e & 7, lane = (e >> 3) & 63, kh = (e >> 9) & 1, nt = e >> 10;
            int k = kh * 32 + (lane >> 4) * 8 + j;
            int n = nt * 16 + (lane & 15);
            w2bf[e] = f2bf(W2[k * COUT + n]);
        }
        return;
    }
    if (blockIdx.x == 197) {
        for (int e = threadIdx.x; e < 4096; e += 256) {
            int j = e & 7, lane = (e >> 3) & 63, kh = (e >> 9) & 1, nt = e >> 10;
            int k = kh * 32 + (lane >> 4) * 8 + j;
            int n = nt * 16 + (lane & 15);
            w1bf[e] = f2bf(W1[k * CMID + n]);
        }
        return;
    }
    int i = blockIdx.x * 256 + threadIdx.x;    // uint-pair index over N_PTS/2
    if (i >= N_PTS / 2) return;
    const unsigned int* p = (const unsigned int*)pc;
    unsigned int u = 0;
    #pragma unroll
    for (int s = 0; s < HSLC; s++) u += p[s * (N_PTS / 2) + i];
    float2 r;
    r.x = (float)(u & 0xffffu);
    r.y = (float)(u >> 16);
    ((float2*)counts)[i] = r;
}

// ---- 3. MFMA gemm1: z1b = bf16(feat @ W1 + b1), stats1 fused ----
__global__ __launch_bounds__(256) void gemm1_k(const float* __restrict__ feat,
                                               const unsigned short* __restrict__ w1bf,
                                               const float* __restrict__ b1,
                                               const float* __restrict__ counts,
                                               unsigned short* __restrict__ z1b,
                                               float* __restrict__ S1,
                                               float* __restrict__ Q1) {
    int lane = threadIdx.x & 63, wid = threadIdx.x >> 6;
    int il = lane & 15, quad = lane >> 4;

    bf16x8 wf[4][2];
    const uint4* wp = (const uint4*)w1bf;
    #pragma unroll
    for (int nt = 0; nt < 4; nt++) {
        U8 t0; t0.u = wp[(nt * 2 + 0) * 64 + lane]; wf[nt][0] = t0.v;
        U8 t1; t1.u = wp[(nt * 2 + 1) * 64 + lane]; wf[nt][1] = t1.v;
    }
    float bias[4];
    #pragma unroll
    for (int nt = 0; nt < 4; nt++) bias[nt] = b1[nt * 16 + il];

    float s[4] = {0, 0, 0, 0}, q[4] = {0, 0, 0, 0};

    int wgid = blockIdx.x * 4 + wid;
    for (int tile = wgid; tile < N_PTS / 16; tile += gridDim.x * 4) {
        int m0 = tile * 16;
        const float* fr = feat + (size_t)(m0 + il) * 64;
        float4 fa = *(const float4*)(fr + quad * 8);
        float4 fb = *(const float4*)(fr + quad * 8 + 4);
        float4 fc = *(const float4*)(fr + 32 + quad * 8);
        float4 fd = *(const float4*)(fr + 32 + quad * 8 + 4);
        U8 ua, ub;
        ua.s[0] = f2bf(fa.x); ua.s[1] = f2bf(fa.y); ua.s[2] = f2bf(fa.z); ua.s[3] = f2bf(fa.w);
        ua.s[4] = f2bf(fb.x); ua.s[5] = f2bf(fb.y); ua.s[6] = f2bf(fb.z); ua.s[7] = f2bf(fb.w);
        ub.s[0] = f2bf(fc.x); ub.s[1] = f2bf(fc.y); ub.s[2] = f2bf(fc.z); ub.s[3] = f2bf(fc.w);
        ub.s[4] = f2bf(fd.x); ub.s[5] = f2bf(fd.y); ub.s[6] = f2bf(fd.z); ub.s[7] = f2bf(fd.w);

        float4 cnt4 = *(const float4*)(counts + m0 + quad * 4);
        #pragma unroll
        for (int nt = 0; nt < 4; nt++) {
            f32x4 acc = {bias[nt], bias[nt], bias[nt], bias[nt]};
            acc = __builtin_amdgcn_mfma_f32_16x16x32_bf16(ua.v, wf[nt][0], acc, 0, 0, 0);
            acc = __builtin_amdgcn_mfma_f32_16x16x32_bf16(ub.v, wf[nt][1], acc, 0, 0, 0);
            // C/D: col = il (channel nt*16+il), row = m0 + quad*4 + reg
            unsigned short* zp = z1b + (size_t)(m0 + quad * 4) * 64 + nt * 16 + il;
            zp[0]   = f2bf(acc[0]);
            zp[64]  = f2bf(acc[1]);
            zp[128] = f2bf(acc[2]);
            zp[192] = f2bf(acc[3]);
            s[nt] += cnt4.x * acc[0] + cnt4.y * acc[1] + cnt4.z * acc[2] + cnt4.w * acc[3];
            q[nt] += cnt4.x * acc[0] * acc[0] + cnt4.y * acc[1] * acc[1]
                   + cnt4.z * acc[2] * acc[2] + cnt4.w * acc[3] * acc[3];
        }
    }
    #pragma unroll
    for (int m = 16; m <= 32; m <<= 1) {
        #pragma unroll
        for (int nt = 0; nt < 4; nt++) {
            s[nt] += __shfl_xor(s[nt], m, 64);
            q[nt] += __shfl_xor(q[nt], m, 64);
        }
    }
    __shared__ float sred[2][4][4][16];        // [s/q][wave][nt][il]
    if (quad == 0) {
        #pragma unroll
        for (int nt = 0; nt < 4; nt++) { sred[0][wid][nt][il] = s[nt]; sred[1][wid][nt][il] = q[nt]; }
    }
    __syncthreads();
    if (threadIdx.x < 128) {
        int which = threadIdx.x >> 6, c = threadIdx.x & 63;
        float t = sred[which][0][c >> 4][c & 15] + sred[which][1][c >> 4][c & 15]
                + sred[which][2][c >> 4][c & 15] + sred[which][3][c >> 4][c & 15];
        atomicAdd(which ? &Q1[c] : &S1[c], t);
    }
}

// ---- 4. MFMA gemm2: z2b = bf16( relu(z1*A1+B1) @ W2 + b2 ), stats2 fused ----
__device__ __forceinline__ bf16x8 bnrelu(uint4 r, float4 alo, float4 ahi,
                                         float4 blo, float4 bhi) {
    float z0 = __uint_as_float(r.x << 16), z1 = __uint_as_float(r.x & 0xffff0000u);
    float z2 = __uint_as_float(r.y << 16), z3 = __uint_as_float(r.y & 0xffff0000u);
    float z4 = __uint_as_float(r.z << 16), z5 = __uint_as_float(r.z & 0xffff0000u);
    float z6 = __uint_as_float(r.w << 16), z7 = __uint_as_float(r.w & 0xffff0000u);
    U8 o;
    o.s[0] = f2bf(fmaxf(fmaf(alo.x, z0, blo.x), 0.f));
    o.s[1] = f2bf(fmaxf(fmaf(alo.y, z1, blo.y), 0.f));
    o.s[2] = f2bf(fmaxf(fmaf(alo.z, z2, blo.z), 0.f));
    o.s[3] = f2bf(fmaxf(fmaf(alo.w, z3, blo.w), 0.f));
    o.s[4] = f2bf(fmaxf(fmaf(ahi.x, z4, bhi.x), 0.f));
    o.s[5] = f2bf(fmaxf(fmaf(ahi.y, z5, bhi.y), 0.f));
    o.s[6] = f2bf(fmaxf(fmaf(ahi.z, z6, bhi.z), 0.f));
    o.s[7] = f2bf(fmaxf(fmaf(ahi.w, z7, bhi.w), 0.f));
    return o.v;
}

__global__ __launch_bounds__(256) void gemm2_k(const unsigned short* __restrict__ z1b,
                                               const unsigned short* __restrict__ w2bf,
                                               const float* __restrict__ S1,
                                               const float* __restrict__ Q1,
                                               const float* __restrict__ g1,
                                               const float* __restrict__ be1,
                                               const float* __restrict__ b2,
                                               const float* __restrict__ counts,
                                               unsigned short* __restrict__ z2b,
                                               float* __restrict__ S2,
                                               float* __restrict__ Q2) {
    __shared__ float Al[64], Bl[64];
    if (threadIdx.x < 64) {
        const float inv = 1.0f / (float)NK;
        float m = S1[threadIdx.x] * inv;
        float v = Q1[threadIdx.x] * inv - m * m;
        float a = g1[threadIdx.x] * rsqrtf(v + 1e-5f);
        Al[threadIdx.x] = a;
        Bl[threadIdx.x] = be1[threadIdx.x] - m * a;
    }
    __syncthreads();

    int lane = threadIdx.x & 63, wid = threadIdx.x >> 6;
    int il = lane & 15, quad = lane >> 4;

    float4 a0lo = *(const float4*)(Al + quad * 8);
    float4 a0hi = *(const float4*)(Al + quad * 8 + 4);
    float4 b0lo = *(const float4*)(Bl + quad * 8);
    float4 b0hi = *(const float4*)(Bl + quad * 8 + 4);
    float4 a1lo = *(const float4*)(Al + 32 + quad * 8);
    float4 a1hi = *(const float4*)(Al + 32 + quad * 8 + 4);
    float4 b1lo = *(const float4*)(Bl + 32 + quad * 8);
    float4 b1hi = *(const float4*)(Bl + 32 + quad * 8 + 4);

    bf16x8 bfr[8][2];
    const uint4* wp = (const uint4*)w2bf;
    #pragma unroll
    for (int nt = 0; nt < 8; nt++) {
        U8 t0; t0.u = wp[(nt * 2 + 0) * 64 + lane]; bfr[nt][0] = t0.v;
        U8 t1; t1.u = wp[(nt * 2 + 1) * 64 + lane]; bfr[nt][1] = t1.v;
    }
    float bias[8];
    #pragma unroll
    for (int nt = 0; nt < 8; nt++) bias[nt] = b2[nt * 16 + il];

    float s[8], q[8];
    #pragma unroll
    for (int j = 0; j < 8; j++) { s[j] = 0.f; q[j] = 0.f; }

    int wgid = blockIdx.x * 4 + wid;
    for (int tile = wgid; tile < N_PTS / 16; tile += gridDim.x * 4) {
        int m0 = tile * 16;
        const uint4* ar = (const uint4*)(z1b + (size_t)(m0 + il) * 64);
        uint4 ra0 = ar[quad];
        uint4 ra1 = ar[4 + quad];
        bf16x8 af0 = bnrelu(ra0, a0lo, a0hi, b0lo, b0hi);
        bf16x8 af1 = bnrelu(ra1, a1lo, a1hi, b1lo, b1hi);
        float4 cnt4 = *(const float4*)(counts + m0 + quad * 4);
        #pragma unroll
        for (int nt = 0; nt < 8; nt++) {
            f32x4 acc = {bias[nt], bias[nt], bias[nt], bias[nt]};
            acc = __builtin_amdgcn_mfma_f32_16x16x32_bf16(af0, bfr[nt][0], acc, 0, 0, 0);
            acc = __builtin_amdgcn_mfma_f32_16x16x32_bf16(af1, bfr[nt][1], acc, 0, 0, 0);
            // half-split layout: z2b[half][row][64], half = nt>>2
            unsigned short* zp = z2b + ((size_t)(nt >> 2) * N_PTS + m0 + quad * 4) * 64
                                     + (nt & 3) * 16 + il;
            zp[0]   = f2bf(acc[0]);
            zp[64]  = f2bf(acc[1]);
            zp[128] = f2bf(acc[2]);
            zp[192] = f2bf(acc[3]);
            s[nt] += cnt4.x * acc[0] + cnt4.y * acc[1] + cnt4.z * acc[2] + cnt4.w * acc[3];
            q[nt] += cnt4.x * acc[0] * acc[0] + cnt4.y * acc[1] * acc[1]
                   + cnt4.z * acc[2] * acc[2] + cnt4.w * acc[3] * acc[3];
        }
    }
    #pragma unroll
    for (int m = 16; m <= 32; m <<= 1) {
        #pragma unroll
        for (int nt = 0; nt < 8; nt++) {
            s[nt] += __shfl_xor(s[nt], m, 64);
            q[nt] += __shfl_xor(q[nt], m, 64);
        }
    }
    __shared__ float sred[2][4][8][16];        // [s/q][wave][nt][il]
    if (quad == 0) {
        #pragma unroll
        for (int nt = 0; nt < 8; nt++) { sred[0][wid][nt][il] = s[nt]; sred[1][wid][nt][il] = q[nt]; }
    }
    __syncthreads();
    {
        int which = threadIdx.x >> 7, c = threadIdx.x & 127;
        // channel c corresponds to output column: c = nt*16+il
        float t = sred[which][0][c >> 4][c & 15] + sred[which][1][c >> 4][c & 15]
                + sred[which][2][c >> 4][c & 15] + sred[which][3][c >> 4][c & 15];
        atomicAdd(which ? &Q2[c] : &S2[c], t);
    }
}

// ---- 5. gather + fused BN2/relu/max, half-major for L2 locality ----
// z2b[half][row][64]; 2 points per wave (32 lanes each); out[n, half*64 + c]
__global__ __launch_bounds__(256) void gather_k(const unsigned int* __restrict__ z2u,
                                                const int* __restrict__ idx,
                                                const float* __restrict__ S2,
                                                const float* __restrict__ Q2,
                                                const float* __restrict__ g2,
                                                const float* __restrict__ be2,
                                                float* __restrict__ out) {
    int lane = threadIdx.x & 63, wid = threadIdx.x >> 6;
    int half = blockIdx.x / (N_PTS / 8);
    int n    = (blockIdx.x % (N_PTS / 8)) * 8 + wid * 2 + (lane >> 5);
    int sl   = lane & 31;

    const float inv = 1.0f / (float)NK;
    float2 Sv = ((const float2*)S2)[half * 32 + sl];
    float2 Qv = ((const float2*)Q2)[half * 32 + sl];
    float2 gv = ((const float2*)g2)[half * 32 + sl];
    float2 bv = ((const float2*)be2)[half * 32 + sl];
    float m0c = Sv.x * inv, m1c = Sv.y * inv;
    float a0 = gv.x * rsqrtf(Qv.x * inv - m0c * m0c + 1e-5f);
    float a1 = gv.y * rsqrtf(Qv.y * inv - m1c * m1c + 1e-5f);
    float b0 = bv.x - m0c * a0;
    float b1 = bv.y - m1c * a1;

    const int* ip = idx + n * KNN;
    const unsigned int* zh = z2u + (size_t)half * N_PTS * 32;
    float mx0 = -1e30f, mn0 = 1e30f, mx1 = -1e30f, mn1 = 1e30f;
    #pragma unroll
    for (int k = 0; k < KNN; k++) {
        int j = ip[k];
        unsigned v = zh[(size_t)j * 32 + sl];
        float f0 = __uint_as_float(v << 16);
        float f1 = __uint_as_float(v & 0xffff0000u);
        mx0 = fmaxf(mx0, f0); mn0 = fminf(mn0, f0);
        mx1 = fmaxf(mx1, f1); mn1 = fminf(mn1, f1);
    }
    float2 r;
    r.x = fmaxf(fmaxf(fmaf(a0, mx0, b0), fmaf(a0, mn0, b0)), 0.f);
    r.y = fmaxf(fmaxf(fmaf(a1, mx1, b1), fmaf(a1, mn1, b1)), 0.f);
    ((float2*)(out + (size_t)n * COUT + half * 64))[sl] = r;
}

extern "C" void kernel_launch(void* const* d_in, const int* in_sizes, int n_in,
                              void* d_out, int out_size, void* d_ws, size_t ws_size,
                              hipStream_t stream) {
    const float* feat = (const float*)d_in[0];
    const int*   idx  = (const int*)d_in[1];
    const float* W1   = (const float*)d_in[2];
    const float* b1   = (const float*)d_in[3];
    const float* g1   = (const float*)d_in[4];
    const float* be1  = (const float*)d_in[5];
    const float* W2   = (const float*)d_in[6];
    const float* b2   = (const float*)d_in[7];
    const float* g2   = (const float*)d_in[8];
    const float* be2  = (const float*)d_in[9];
    float* out = (float*)d_out;

    char* ws = (char*)d_ws;
    unsigned short* z2b = (unsigned short*)(ws + OFF_Z2B);
    unsigned short* pc  = (unsigned short*)(ws + OFF_Z2B);   // alias, dead before gemm2
    unsigned short* z1b = (unsigned short*)(ws + OFF_Z1B);
    float* counts = (float*)(ws + OFF_CNT);
    float* S1 = (float*)(ws + OFF_STATS);
    float* Q1 = S1 + 64;
    float* S2 = S1 + 128;
    float* Q2 = S1 + 256;
    unsigned short* w2bf = (unsigned short*)(ws + OFF_W2BF);
    unsigned short* w1bf = (unsigned short*)(ws + OFF_W1BF);

    hipMemsetAsync(ws + OFF_STATS, 0, 1536, stream);

    hist_k<<<4 * HSLC, 256, 0, stream>>>(idx, pc);
    sum_counts_k<<<198, 256, 0, stream>>>(pc, counts, W2, w2bf, W1, w1bf);
    gemm1_k<<<512, 256, 0, stream>>>(feat, w1bf, b1, counts, z1b, S1, Q1);
    gemm2_k<<<512, 256, 0, stream>>>(z1b, w2bf, S1, Q1, g1, be1, b2, counts, z2b, S2, Q2);
    gather_k<<<2 * (N_PTS / 8), 256, 0, stream>>>((const unsigned int*)z2b, idx,
                                                  S2, Q2, g2, be2, out);
}